// Round 1
// baseline (1565.561 us; speedup 1.0000x reference)
//
#include <hip/hip_runtime.h>
#include <hip/hip_bf16.h>
#include <math.h>

#define BB 20
#define CC 60
#define HH 264
#define WW 264
#define HWW (HH * WW)

// ---------------------------------------------------------------------------
// Kernel 1: adaptive avg-pool to 3x3 (exact 88x88 block means)
// grid = B*C = 1200 blocks, 256 threads
// ---------------------------------------------------------------------------
__global__ __launch_bounds__(256) void gap_kernel(const float* __restrict__ x,
                                                  float* __restrict__ x_gap) {
    const int bc = blockIdx.x;                 // b*60 + c
    const float* xp = x + (size_t)bc * HWW;
    const int tid = threadIdx.x;

    __shared__ float red[3][128];              // [gw][padded col-group]
    // zero-init pad region once (cols >= 88 never written)
    for (int i = tid; i < 3 * 128; i += 256) ((float*)red)[i] = 0.f;
    __syncthreads();

    const int gw0 = tid / 88;                  // column group of column `tid`
    const int p0  = tid - 88 * gw0;

    for (int gh = 0; gh < 3; ++gh) {
        float a0 = 0.f, a1 = 0.f;
        const int h0 = gh * 88;
        for (int h = h0; h < h0 + 88; ++h) {
            const float* row = xp + h * WW;
            a0 += row[tid];
            if (tid < 8) a1 += row[256 + tid]; // columns 256..263 (group 2)
        }
        red[gw0][p0] = a0;
        if (tid < 8) red[2][80 + tid] = a1;    // pos 80..87 of group 2
        __syncthreads();
        if (tid < 192) {
            const int gw = tid >> 6, c = tid & 63;
            float v = red[gw][c] + red[gw][c + 64];
            for (int off = 32; off; off >>= 1) v += __shfl_down(v, off);
            if (c == 0) x_gap[bc * 9 + gh * 3 + gw] = v * (1.0f / 7744.0f);
        }
        __syncthreads();
    }
}

// ---------------------------------------------------------------------------
// Kernel 2: build effective filter G[gi][tap][o]  (gi=20g+ic, 60*9*60 floats)
// grid = 9 blocks (one per tap), 256 threads
// ---------------------------------------------------------------------------
__global__ __launch_bounds__(256) void filt_kernel(
    const float* __restrict__ xg,
    const float* __restrict__ w1, const float* __restrict__ b1,
    const float* __restrict__ w2, const float* __restrict__ b2,
    const float* __restrict__ w3, const float* __restrict__ b3,
    const float* __restrict__ p1, const float* __restrict__ p2,
    const float* __restrict__ p3,
    const float* __restrict__ w_out, float* __restrict__ G) {
    const int tap = blockIdx.x;
    const int tid = threadIdx.x;
    __shared__ float t[3][20][20];             // [g][oc][ic]

    for (int i = tid; i < 3 * 20 * 20; i += 256) {
        const int g = i / 400;
        const int rem = i - g * 400;
        const int oc = rem / 20;
        const int ic = rem - oc * 20;
        const float* wg = (g == 0) ? w1 : (g == 1) ? w2 : w3;
        const float* bg = (g == 0) ? b1 : (g == 1) ? b2 : b3;
        const float pg  = (g == 0) ? p1[0] : (g == 1) ? p2[0] : p3[0];
        float s = bg[ic];
        for (int c = 0; c < 60; ++c)
            s += xg[(oc * 60 + c) * 9 + tap] * wg[ic * 60 + c];
        t[g][oc][ic] = tanhf(pg * s);
    }
    __syncthreads();

    for (int i = tid; i < 60 * 60; i += 256) {
        const int gi = i / 60;
        const int o  = i - gi * 60;
        const int g  = gi / 20;
        const int ic = gi - g * 20;
        float s = 0.f;
        for (int oc = 0; oc < 20; ++oc)
            s += w_out[o * 60 + 20 * g + oc] * t[g][oc][ic];
        G[(gi * 9 + tap) * 60 + o] = s;
    }
}

// ---------------------------------------------------------------------------
// Kernel 3: the fused conv.  out[b,o,h,w] = sum_{gi,tap} x * G + b_out
// 512 threads: waves 0-3 handle o in [0,30), waves 4-7 o in [30,60),
// both covering the same 16x16 spatial tile. x staged in LDS in 20-channel
// chunks (row stride 24 floats -> exactly 2-way bank aliasing = free).
// G reads are wave-uniform -> s_load, one SGPR operand per v_fma_f32.
// ---------------------------------------------------------------------------
#define TILE   16
#define TILES  17   // ceil(264/16)
#define XS_RS  24   // LDS row stride (floats)
#define XS_CS  (18 * XS_RS)

__global__ __launch_bounds__(512) void conv_kernel(
    const float* __restrict__ x, const float* __restrict__ G,
    const float* __restrict__ b_out, float* __restrict__ out) {
    __shared__ float xs[20 * XS_CS];           // 20 ch * 18 rows * 24 floats

    const int blk = blockIdx.x;
    const int b   = blk / (TILES * TILES);
    const int tt  = blk - b * (TILES * TILES);
    const int ty0 = (tt / TILES) * TILE;
    const int tx0 = (tt - (tt / TILES) * TILES) * TILE;

    const int tid = threadIdx.x;
    const int half = __builtin_amdgcn_readfirstlane(tid >> 8); // wave-uniform
    const int o_base = half * 30;
    const int pix = tid & 255;
    const int px = pix & 15;
    const int py = pix >> 4;

    float acc[30];
#pragma unroll
    for (int i = 0; i < 30; ++i) acc[i] = 0.f;

    const float* xb = x + (size_t)b * CC * HWW;

    for (int chunk = 0; chunk < 3; ++chunk) {
        const int c0 = chunk * 20;
        __syncthreads();
        // stage 20 channels x 18x18 halo tile (zero-padded at borders)
        for (int i = tid; i < 20 * 18 * 18; i += 512) {
            const int c   = i / 324;
            const int rem = i - c * 324;
            const int r   = rem / 18;
            const int col = rem - r * 18;
            const int gh = ty0 - 1 + r;
            const int gw = tx0 - 1 + col;
            float v = 0.f;
            if ((unsigned)gh < HH && (unsigned)gw < WW)
                v = xb[(size_t)(c0 + c) * HWW + gh * WW + gw];
            xs[c * XS_CS + r * XS_RS + col] = v;
        }
        __syncthreads();

#pragma unroll 1
        for (int c = 0; c < 20; ++c) {
            const int gi = c0 + c;
            float xv[9];
#pragma unroll
            for (int dy = 0; dy < 3; ++dy)
#pragma unroll
                for (int dx = 0; dx < 3; ++dx)
                    xv[dy * 3 + dx] = xs[c * XS_CS + (py + dy) * XS_RS + (px + dx)];
            const float* gptr = G + gi * 540 + o_base;
#pragma unroll
            for (int tap = 0; tap < 9; ++tap) {
#pragma unroll
                for (int o = 0; o < 30; ++o)
                    acc[o] = fmaf(xv[tap], gptr[tap * 60 + o], acc[o]);
            }
        }
    }

    const int h = ty0 + py, w = tx0 + px;
    if (h < HH && w < WW) {
        const size_t base = ((size_t)b * CC + o_base) * HWW + (size_t)h * WW + w;
#pragma unroll
        for (int o = 0; o < 30; ++o)
            out[base + (size_t)o * HWW] = acc[o] + b_out[o_base + o];
    }
}

// ---------------------------------------------------------------------------
extern "C" void kernel_launch(void* const* d_in, const int* in_sizes, int n_in,
                              void* d_out, int out_size, void* d_ws, size_t ws_size,
                              hipStream_t stream) {
    const float* x     = (const float*)d_in[0];
    const float* w1    = (const float*)d_in[1];
    const float* b1    = (const float*)d_in[2];
    const float* w2    = (const float*)d_in[3];
    const float* b2    = (const float*)d_in[4];
    const float* w3    = (const float*)d_in[5];
    const float* b3    = (const float*)d_in[6];
    const float* p1    = (const float*)d_in[7];
    const float* p2    = (const float*)d_in[8];
    const float* p3    = (const float*)d_in[9];
    const float* w_out = (const float*)d_in[10];
    const float* b_out = (const float*)d_in[11];
    float* out = (float*)d_out;

    float* ws  = (float*)d_ws;
    float* xg  = ws;            // 20*60*9   = 10800 floats
    float* G   = ws + 10800;    // 60*9*60   = 32400 floats

    gap_kernel<<<BB * CC, 256, 0, stream>>>(x, xg);
    filt_kernel<<<9, 256, 0, stream>>>(xg, w1, b1, w2, b2, w3, b3,
                                       p1, p2, p3, w_out, G);
    conv_kernel<<<BB * TILES * TILES, 512, 0, stream>>>(x, G, b_out, out);
}